// Round 11
// baseline (4150.022 us; speedup 1.0000x reference)
//
#include <hip/hip_runtime.h>
#include <cfloat>
#include <math.h>

#define NOBS   256
#define NY     50
#define NX     30
#define NITER  400
#define LRATE  0.05f
#define CSTR   260     // ep_t column stride (floats), init staging
#define THRANK 40      // theta tracks the rank-40 KEY -> C = 41 every valid iter
#define WSLOT  16      // candidate slots per 64-obs window (overflow -> exact fallback)

__device__ __forceinline__ float rl_f(float x, int k) {
  return __int_as_float(__builtin_amdgcn_readlane(__float_as_int(x), k));
}
__device__ __forceinline__ unsigned long long rl_u64(unsigned long long x, int k) {
  const unsigned lo = (unsigned)__builtin_amdgcn_readlane((int)(unsigned)(x & 0xffffffffull), k);
  const unsigned hi = (unsigned)__builtin_amdgcn_readlane((int)(unsigned)(x >> 32), k);
  return ((unsigned long long)hi << 32) | lo;
}

#define DPP_MAXSTEP(x, ctrl)                                                       \
  x = fmaxf(x, __int_as_float(__builtin_amdgcn_update_dpp(                         \
        __float_as_int(x), __float_as_int(x), (ctrl), 0xF, 0xF, false)))

// R8 trunk (er[25] A/B halves, 92 VGPRs — the proven no-spill envelope; R9/R10 showed
// er[50]@512thr always spills) + de-barriered tail: full-64 lane-held rank scan,
// two-accumulator atomic backward (defers a/cm so tie-count rides an atomic too),
// replicated projection. 3 barriers/iter (R8 had 6), 2 LDS round-trips (had 5).
__global__ __launch_bounds__(512) __attribute__((amdgpu_waves_per_eu(2, 2)))
void dro_kernel(
    const float* __restrict__ X, const float* __restrict__ Y,
    const float* __restrict__ W, const float* __restrict__ Bb,
    const float* __restrict__ DLT, const float* __restrict__ GMM,
    float* __restrict__ out)
{
  __shared__ __align__(16) float ep_t[51 * CSTR];          // init staging (dead after epb load)
  __shared__ __align__(16) unsigned long long rrk[NOBS];   // full keys (exact fallback)
  __shared__ __align__(16) unsigned long long ckey[64];    // 4 windows x 16 fixed slots
  __shared__ __align__(16) float pex[512];                 // forward half-dot exchange
  __shared__ __align__(16) float red[64];                  // base-coef column sums (atomic)
  __shared__ __align__(16) float redt[64];                 // tie-coef column sums (atomic)
  __shared__ float wmax4[4];
  __shared__ int   vcnt4[4];                               // candidates per window
  __shared__ int   sh_tie;                                 // global max-tie count (atomic)
  __shared__ unsigned long long th_key;

  const int tid  = threadIdx.x;      // 0..511
  const int oid  = tid & 255;        // owned observation
  const int half = tid >> 8;         // 0 = A (publisher), 1 = B (replica)
  const int lane = tid & 63;
  const int w8   = tid >> 6;         // wave 0..7
  const int wsc  = w8 & 3;           // obs window (obs wsc*64 + lane)
  const int t    = blockIdx.x;       // scenario
  const int jbase = half * 25;

  const float delta = DLT[0];
  const float gamma = GMM[0];
  const float a     = fminf(delta * 0.5f, 255.0f / 256.0f);
  const float a256  = a * 256.0f;

  // ---- init: 25-column slice of owned obs row; stage ep for epb ----
  float er[25];
  {
    float xr[NX];
    #pragma unroll
    for (int k = 0; k < NX; ++k) xr[k] = X[oid * NX + k];
    #pragma unroll
    for (int jj = 0; jj < 25; ++jj) {              // W/B wave-uniform -> scalar loads
      const int j = jbase + jj;
      float acc = Bb[j];
      #pragma unroll
      for (int k = 0; k < NX; ++k) acc = fmaf(xr[k], W[j * NX + k], acc);
      const float e = Y[oid * NY + j] - acc;
      er[jj] = e;
      ep_t[j * CSTR + oid] = e;
    }
    if (half == 1) ep_t[NY * CSTR + oid] = 1.0f;   // ones column -> c gradient
  }
  float yhl;                                       // y_hat row t, per-lane copy
  {
    const int jr = (lane < NY) ? lane : 0;
    float acc = Bb[jr];
    #pragma unroll
    for (int k = 0; k < NX; ++k) acc = fmaf(X[t * NX + k], W[jr * NX + k], acc);
    yhl = acc;
    if (tid < NY) out[NOBS * NY + t * NY + tid] = acc;
  }
  if (tid == 0) { th_key = ~0ull; }                // iter 0 -> exact fallback
  if (tid < 64) ckey[tid] = ~0ull;
  __syncthreads();

  // epb: iteration-invariant backward slice in registers.
  // Wave (half,wsc), lane l: column min(l,50), obs [wsc*64 + half*32, +32).
  float epb[32];
  {
    const int colc = (lane < 51) ? lane : 50;
    const float* ebase = &ep_t[colc * CSTR + wsc * 64 + half * 32];
    #pragma unroll
    for (int q = 0; q < 8; ++q) {
      const float4 e4 = *(const float4*)&ebase[4 * q];
      epb[4*q+0] = e4.x; epb[4*q+1] = e4.y; epb[4*q+2] = e4.z; epb[4*q+3] = e4.w;
    }
  }

  float zv = (lane < NY) ? (1.0f / NY) : 0.0f;     // z one entry/lane, replicated per wave
  float cc = 0.0f;                                 // c, wave-uniform, bit-identical

  #pragma unroll 1
  for (int it = 0; it < NITER; ++it) {
    // ---- P0: forward half-dot (25 terms) ----
    const unsigned long long thk = th_key;         // write was P2 prev iter; B3+B1 separate
    float s0 = 0.f, s1 = 0.f, s2 = 0.f, s3 = 0.f;
    #pragma unroll
    for (int jj = 0; jj < 24; jj += 4) {
      s0 = fmaf(er[jj + 0], rl_f(zv, jbase + jj + 0), s0);
      s1 = fmaf(er[jj + 1], rl_f(zv, jbase + jj + 1), s1);
      s2 = fmaf(er[jj + 2], rl_f(zv, jbase + jj + 2), s2);
      s3 = fmaf(er[jj + 3], rl_f(zv, jbase + jj + 3), s3);
    }
    s0 = fmaf(er[24], rl_f(zv, jbase + 24), s0);
    const float sown = (s0 + s2) + (s1 + s3);
    pex[tid] = sown;
    __syncthreads();                               // B1: pex

    // ---- P1: combine -> u,r,key; window max; candidates into FIXED slots; zero bufs ----
    const float soth = pex[(half ^ 1) * 256 + oid];      // other half's partial
    const float u = (half ? (soth + sown) : (sown + soth)) - cc;  // (sA+sB)-cc, bit-identical
    const float r = u * u;
    const unsigned long long key =
        ((unsigned long long)(unsigned)__float_as_int(r) << 32) | (unsigned)oid;
    if (half == 0) rrk[oid] = key;

    float m = r;                                   // window max (wave's lanes cover window)
    DPP_MAXSTEP(m, 0x111); DPP_MAXSTEP(m, 0x112);
    DPP_MAXSTEP(m, 0x114); DPP_MAXSTEP(m, 0x118);
    DPP_MAXSTEP(m, 0x142); DPP_MAXSTEP(m, 0x143);
    if (half == 0 && lane == 63) wmax4[wsc] = m;

    const bool cond = (key <= thk);
    const unsigned long long cmask = __ballot(cond);
    const int cpos = __popcll(cmask & ((1ull << lane) - 1ull));
    if (half == 0 && lane == 0) vcnt4[wsc] = __popcll(cmask);
    if (half == 0 && cond && cpos < WSLOT) ckey[wsc * WSLOT + cpos] = key;
    if (w8 == 1) red[lane]  = 0.0f;                // zero (read prev P3; B1 separates)
    if (w8 == 2) redt[lane] = 0.0f;
    if (tid == 0) sh_tie = 0;
    __syncthreads();                               // B2: pex-read-done, rrk, wmax4, vcnt4, ckey, zeros

    // ---- P2: validity; ties (atomic); full-64 rank scan; theta; backward (atomic) ----
    const int v0 = vcnt4[0], v1 = vcnt4[1], v2 = vcnt4[2], v3 = vcnt4[3];
    const int C  = v0 + v1 + v2 + v3;
    const bool ovf   = (v0 > WSLOT) | (v1 > WSLOT) | (v2 > WSLOT) | (v3 > WSLOT);
    const bool valid = (!ovf) && ((float)C >= a256);

    const float mx = fmaxf(fmaxf(wmax4[0], wmax4[1]), fmaxf(wmax4[2], wmax4[3]));
    const bool ismax = (r == mx);
    const unsigned long long mmask = __ballot(ismax);   // all lanes (R3 lesson)
    if (half == 0 && lane == 0) atomicAdd(&sh_tie, __popcll(mmask));

    int cnt;
    if (__builtin_expect(valid, 1)) {
      const unsigned long long ck = ckey[lane];    // all 64 slots lane-held; 1 ds_read_b64
      int c0 = 0, c1 = 0, c2 = 0, c3 = 0;
      #pragma unroll
      for (int s = 0; s < 64; s += 4) {            // sentinels never count
        c0 += (rl_u64(ck, s + 0) < key) ? 1 : 0;
        c1 += (rl_u64(ck, s + 1) < key) ? 1 : 0;
        c2 += (rl_u64(ck, s + 2) < key) ? 1 : 0;
        c3 += (rl_u64(ck, s + 3) < key) ? 1 : 0;
      }
      cnt = (c0 + c2) + (c1 + c3);                 // cand: exact rank; non-cand: C (>=aN)
    } else {                                       // iter 0 / overflow: exact full scan
      int c0 = 0, c1 = 0, c2 = 0, c3 = 0;
      const ulonglong2* p = (const ulonglong2*)&rrk[0];
      #pragma unroll 8
      for (int j = 0; j < 128; j += 2) {
        const ulonglong2 ka = p[j], kb = p[j + 1];
        c0 += (ka.x < key) ? 1 : 0;
        c1 += (ka.y < key) ? 1 : 0;
        c2 += (kb.x < key) ? 1 : 0;
        c3 += (kb.y < key) ? 1 : 0;
      }
      cnt = (c0 + c2) + (c1 + c3);
    }
    if (half == 0 && cnt == THRANK && (!valid || cond)) th_key = key;  // unique writer

    // coef split: coef = cb + (a/cm)*ct, cm folded in at P3 when sh_tie is final
    const float gfac = fminf(fmaxf((float)cnt + 1.0f - a256, 0.0f), 1.0f) * (1.0f / 256.0f);
    const float cb   = 2.0f * u * gfac;
    const float ct   = ismax ? (2.0f * u) : 0.0f;

    const int lbase = half * 32;                   // own wave's lanes hold these obs' coef
    float qb0 = 0.f, qb1 = 0.f, qt0 = 0.f, qt1 = 0.f;
    #pragma unroll
    for (int q = 0; q < 8; ++q) {
      qb0 = fmaf(rl_f(cb, lbase + 4 * q + 0), epb[4 * q + 0], qb0);
      qb1 = fmaf(rl_f(cb, lbase + 4 * q + 1), epb[4 * q + 1], qb1);
      qb0 = fmaf(rl_f(cb, lbase + 4 * q + 2), epb[4 * q + 2], qb0);
      qb1 = fmaf(rl_f(cb, lbase + 4 * q + 3), epb[4 * q + 3], qb1);
      qt0 = fmaf(rl_f(ct, lbase + 4 * q + 0), epb[4 * q + 0], qt0);
      qt1 = fmaf(rl_f(ct, lbase + 4 * q + 1), epb[4 * q + 1], qt1);
      qt0 = fmaf(rl_f(ct, lbase + 4 * q + 2), epb[4 * q + 2], qt0);
      qt1 = fmaf(rl_f(ct, lbase + 4 * q + 3), epb[4 * q + 3], qt1);
    }
    atomicAdd(&red[lane],  qb0 + qb1);             // ds_add_f32
    atomicAdd(&redt[lane], qt0 + qt1);
    __syncthreads();                               // B3: red, redt, sh_tie, th_key

    // ---- P3: combine; step; full replicated projection; sentinel refill ----
    const float amax = a / (float)sh_tie;
    const float s4 = red[lane] + amax * redt[lane];  // lane j: grad_j; lane 50: sum(coef)
    cc = cc + LRATE * rl_f(s4, NY);                // gc = -sum(coef)
    const float gz = s4 - gamma * yhl;
    const float v  = zv - LRATE * gz;

    int ah0 = 0, ah1 = 0; float cs0 = 0.f, cs1 = 0.f;
    #pragma unroll
    for (int k = 0; k < NY; k += 2) {
      const float vk0 = rl_f(v, k);
      const float vk1 = rl_f(v, k + 1);
      const bool b0 = (vk0 > v) || (vk0 == v && (k    ) > lane);
      const bool b1 = (vk1 > v) || (vk1 == v && (k + 1) > lane);
      ah0 += b0 ? 1 : 0;
      ah1 += b1 ? 1 : 0;
      cs0 += b0 ? vk0 : 0.0f;
      cs1 += b1 ? vk1 : 0.0f;
    }
    const int   ahead = ah0 + ah1;
    const float css   = (cs0 + cs1) + v - 1.0f;
    const bool pc = (lane < NY) && (v - css / (float)(ahead + 1) > 0.0f);
    const int rho = __popcll(__ballot(pc));        // >= 1 always
    const unsigned long long bsel = __ballot((lane < NY) && (ahead == rho - 1));
    const int srcl = __ffsll(bsel) - 1;
    const float tau =
        __int_as_float(__builtin_amdgcn_readlane(__float_as_int(css), srcl)) / (float)rho;
    zv = (lane < NY) ? fmaxf(v - tau, 0.0f) : 0.0f;

    if (tid < 64) ckey[tid] = ~0ull;               // refill: read was P2 (B3 separates);
                                                   // next slot-write is P1 next iter (B1 separates)
  }

  if (tid < 64 && lane < NY) out[t * NY + lane] = zv;   // wave 0

}

extern "C" void kernel_launch(void* const* d_in, const int* in_sizes, int n_in,
                              void* d_out, int out_size, void* d_ws, size_t ws_size,
                              hipStream_t stream) {
  (void)in_sizes; (void)n_in; (void)d_ws; (void)ws_size; (void)out_size;
  const float* X   = (const float*)d_in[0];
  const float* Y   = (const float*)d_in[1];
  const float* W   = (const float*)d_in[2];
  const float* B   = (const float*)d_in[3];
  const float* DLT = (const float*)d_in[4];
  const float* GMM = (const float*)d_in[5];
  float* out = (float*)d_out;
  hipLaunchKernelGGL(dro_kernel, dim3(NOBS), dim3(512), 0, stream,
                     X, Y, W, B, DLT, GMM, out);
}

// Round 12
// 2675.628 us; speedup vs baseline: 1.5510x; 1.5510x over previous
//
#include <hip/hip_runtime.h>
#include <cfloat>
#include <math.h>

#define NOBS   256
#define NY     50
#define NX     30
#define NITER  400
#define LRATE  0.05f
#define CSTR   260    // ep_t column stride (floats), init staging only
#define THRANK 40     // theta tracks the rank-40 KEY -> C = 41 every valid iter
#define WSLOT  16     // candidate slots per 64-obs window (overflow -> exact fallback)

__device__ __forceinline__ float rl_f(float x, int k) {
  return __int_as_float(__builtin_amdgcn_readlane(__float_as_int(x), k));
}
__device__ __forceinline__ int rl_i(int x, int k) {
  return __builtin_amdgcn_readlane(x, k);
}
__device__ __forceinline__ unsigned long long rl_u64(unsigned long long x, int k) {
  const unsigned lo = (unsigned)__builtin_amdgcn_readlane((int)(unsigned)(x & 0xffffffffull), k);
  const unsigned hi = (unsigned)__builtin_amdgcn_readlane((int)(unsigned)(x >> 32), k);
  return ((unsigned long long)hi << 32) | lo;
}

#define DPP_MAXSTEP(x, ctrl)                                                       \
  x = fmaxf(x, __int_as_float(__builtin_amdgcn_update_dpp(                         \
        __float_as_int(x), __float_as_int(x), (ctrl), 0xF, 0xF, false)))

// One scenario/block, 8 waves (2/SIMD). Thread owns obs (tid&255); A=waves 0-3
// (cols 0..24 + all rank machinery, 1 A-wave/SIMD), B=waves 4-7 (cols 25..49).
// Steady state: NO per-thread rank scan (correction-form gradient), all broadcasts
// via per-wave LDS rows (ds_read_b128 same-address broadcast — no readlane hazards).
// R11 lesson: replicated readlane pairs cost ~5-15cyc each; barriers are cheap.
__global__ __launch_bounds__(512) __attribute__((amdgpu_waves_per_eu(2, 2)))
void dro_kernel(
    const float* __restrict__ X, const float* __restrict__ Y,
    const float* __restrict__ W, const float* __restrict__ Bb,
    const float* __restrict__ DLT, const float* __restrict__ GMM,
    float* __restrict__ out)
{
  __shared__ __align__(16) float ep_t[51 * CSTR];          // init staging for epb (53 KB)
  __shared__ __align__(16) float ep_row[NOBS * 52];        // row-major, col50=1 (53 KB)
  __shared__ __align__(16) unsigned long long rrk[NOBS];   // full keys (fallback)
  __shared__ __align__(16) unsigned long long ckey[64];    // 4 windows x 16 slots
  __shared__ __align__(16) float cu_a[64];                 // u per slot
  __shared__ __align__(16) float pex[512];                 // forward half-dot exchange
  __shared__ __align__(16) int   cex[512];                 // fallback rank exchange
  __shared__ __align__(16) float red12[12 * 64];           // 8 base + 4 correction slots
  __shared__ __align__(16) float cvec8[8 * 64];            // per-wave coef row
  __shared__ __align__(16) float zvec8[8 * 52];            // per-wave z row
  __shared__ __align__(16) float vvec8[8 * 52];            // per-wave v row
  __shared__ float wmax4[4];
  __shared__ int   vcnt4[4];
  __shared__ int   tcnt4[4];
  __shared__ unsigned long long th_key;

  const int tid  = threadIdx.x;      // 0..511
  const int oid  = tid & 255;        // owned observation
  const int half = tid >> 8;         // 0 = A, 1 = B
  const int lane = tid & 63;
  const int w8   = tid >> 6;         // wave 0..7
  const int wsc  = w8 & 3;           // obs window (obs wsc*64 + lane)
  const int t    = blockIdx.x;
  const int jbase = half * 25;

  const float delta = DLT[0];
  const float gamma = GMM[0];
  const float a     = fminf(delta * 0.5f, 255.0f / 256.0f);
  const float a256  = a * 256.0f;

  // ---- init: 25-col slice of owned obs; stage column-major (epb) + row-major (corr) ----
  float er[25];
  {
    float xr[NX];
    #pragma unroll
    for (int k = 0; k < NX; ++k) xr[k] = X[oid * NX + k];
    #pragma unroll
    for (int jj = 0; jj < 25; ++jj) {              // W/B wave-uniform -> scalar loads
      const int j = jbase + jj;
      float acc = Bb[j];
      #pragma unroll
      for (int k = 0; k < NX; ++k) acc = fmaf(xr[k], W[j * NX + k], acc);
      const float e = Y[oid * NY + j] - acc;
      er[jj] = e;
      ep_t[j * CSTR + oid] = e;
      ep_row[oid * 52 + j] = e;
    }
    if (half == 1) {
      ep_t[NY * CSTR + oid] = 1.0f;                // ones column -> c gradient
      ep_row[oid * 52 + NY] = 1.0f;
      ep_row[oid * 52 + 51] = 0.0f;
    }
  }
  float yhl;                                       // y_hat row t, per-lane copy
  {
    const int jr = (lane < NY) ? lane : 0;
    float acc = Bb[jr];
    #pragma unroll
    for (int k = 0; k < NX; ++k) acc = fmaf(X[t * NX + k], W[jr * NX + k], acc);
    yhl = acc;
    if (tid < NY) out[NOBS * NY + t * NY + tid] = acc;
  }
  if (tid == 0) th_key = ~0ull;                    // iter 0 -> fallback
  if (tid < 64) { ckey[tid] = ~0ull; cu_a[tid] = 0.0f; }
  if (lane < 52) {                                 // per-wave z row; pads zero
    zvec8[w8 * 52 + lane] = (lane < NY) ? (1.0f / NY) : 0.0f;
    vvec8[w8 * 52 + lane] = 0.0f;
  }
  __syncthreads();

  // epb: backward slice in registers: col min(lane,50), obs [wsc*64+half*32, +32)
  float epb[32];
  {
    const int colc = (lane < 51) ? lane : 50;
    const float* ebase = &ep_t[colc * CSTR + wsc * 64 + half * 32];
    #pragma unroll
    for (int q = 0; q < 8; ++q) {
      const float4 e4 = *(const float4*)&ebase[4 * q];
      epb[4*q+0] = e4.x; epb[4*q+1] = e4.y; epb[4*q+2] = e4.z; epb[4*q+3] = e4.w;
    }
  }

  float zv = (lane < NY) ? (1.0f / NY) : 0.0f;     // z per lane (for update/projection)
  float cc = 0.0f;                                 // c, wave-uniform

  #pragma unroll 1
  for (int it = 0; it < NITER; ++it) {
    // ---- P0: forward half-dot; z via own-wave LDS row (broadcast b128, no readlane) ----
    const unsigned long long thk = th_key;
    float zq[28];
    {
      const float* zp = &zvec8[w8 * 52 + (half ? 24 : 0)];   // both offsets 16B-aligned
      #pragma unroll
      for (int i = 0; i < 7; ++i) {
        const float4 z4 = *(const float4*)&zp[4 * i];
        zq[4*i+0] = z4.x; zq[4*i+1] = z4.y; zq[4*i+2] = z4.z; zq[4*i+3] = z4.w;
      }
    }
    float s0 = 0.f, s1 = 0.f, s2 = 0.f, s3 = 0.f;
    if (half == 0) {
      #pragma unroll
      for (int jj = 0; jj < 24; jj += 4) {
        s0 = fmaf(er[jj + 0], zq[jj + 0], s0);
        s1 = fmaf(er[jj + 1], zq[jj + 1], s1);
        s2 = fmaf(er[jj + 2], zq[jj + 2], s2);
        s3 = fmaf(er[jj + 3], zq[jj + 3], s3);
      }
      s0 = fmaf(er[24], zq[24], s0);
    } else {                                       // z[25..49] at zq[1..25]
      #pragma unroll
      for (int jj = 0; jj < 24; jj += 4) {
        s0 = fmaf(er[jj + 0], zq[jj + 1], s0);
        s1 = fmaf(er[jj + 1], zq[jj + 2], s1);
        s2 = fmaf(er[jj + 2], zq[jj + 3], s2);
        s3 = fmaf(er[jj + 3], zq[jj + 4], s3);
      }
      s0 = fmaf(er[24], zq[25], s0);
    }
    pex[tid] = (s0 + s2) + (s1 + s3);
    __syncthreads();                               // B1: pex

    // ---- P1: combine -> u,r,key; window max (A); candidate slots (A) ----
    const float u = (pex[oid] + pex[256 + oid]) - cc;    // bit-identical A/B
    const float r = u * u;
    const unsigned long long key =
        ((unsigned long long)(unsigned)__float_as_int(r) << 32) | (unsigned)oid;
    if (half == 0) {
      rrk[oid] = key;
      float m = r;
      DPP_MAXSTEP(m, 0x111); DPP_MAXSTEP(m, 0x112);
      DPP_MAXSTEP(m, 0x114); DPP_MAXSTEP(m, 0x118);
      DPP_MAXSTEP(m, 0x142); DPP_MAXSTEP(m, 0x143);
      if (lane == 63) wmax4[wsc] = m;
    }
    const bool cond = (key <= thk);
    const unsigned long long cmask = __ballot(cond);
    const int cpos = __popcll(cmask & ((1ull << lane) - 1ull));
    if (half == 0 && lane == 0) vcnt4[wsc] = __popcll(cmask);
    if (half == 0 && cond && cpos < WSLOT) {
      ckey[wsc * WSLOT + cpos] = key;
      cu_a[wsc * WSLOT + cpos] = u;
    }
    __syncthreads();                               // B2: rrk, wmax4, vcnt4, ckey, cu

    // ---- P2: validity; ties; A-waves: slot ranks + correction gradient ----
    const int v0 = vcnt4[0], v1 = vcnt4[1], v2 = vcnt4[2], v3 = vcnt4[3];
    const int C  = v0 + v1 + v2 + v3;
    const bool ovf   = (v0 > WSLOT) | (v1 > WSLOT) | (v2 > WSLOT) | (v3 > WSLOT);
    const bool valid = (!ovf) && ((float)C >= a256);

    const float mx = fmaxf(fmaxf(wmax4[0], wmax4[1]), fmaxf(wmax4[2], wmax4[3]));
    const bool ismax = (r == mx);
    const unsigned long long mmask = __ballot(ismax);  // all lanes (R3 lesson)
    if (half == 0 && lane == 0) tcnt4[wsc] = __popcll(mmask);

    if (__builtin_expect(valid, 1)) {
      if (half == 0) {                             // 1 A-wave per SIMD: balanced
        const unsigned long long ck = ckey[lane];  // slot 'lane' held per lane
        const float cuv = cu_a[lane];
        int rk0 = 0, rk1 = 0;
        #pragma unroll
        for (int s = 0; s < 64; s += 2) {          // all-pairs slot ranks (sentinels sink)
          rk0 += (rl_u64(ck, s + 0) < ck) ? 1 : 0;
          rk1 += (rl_u64(ck, s + 1) < ck) ? 1 : 0;
        }
        const int rk = rk0 + rk1;
        if (rk == THRANK && ck != ~0ull) th_key = ck;   // 4 identical writers ✓
        // correction coef for my slot: -2u*clamp(aN-rank,0,1)/N (0 for sentinels)
        const float wc  = fminf(fmaxf(a256 - (float)rk, 0.0f), 1.0f) * (1.0f / 256.0f);
        const float ccf = -2.0f * cuv * wc;
        const int oidx = (int)(unsigned)(ck & 0xffull);
        const int colm = (lane < 51) ? lane : 50;
        float cg = 0.0f;                           // my window's slots only
        #pragma unroll
        for (int s2 = 0; s2 < WSLOT; ++s2) {
          const int s = wsc * WSLOT + s2;
          const float co = rl_f(ccf, s);           // wave-uniform
          if (co != 0.0f) {
            const int ob = rl_i(oidx, s);
            cg = fmaf(co, ep_row[ob * 52 + colm], cg);
          }
        }
        red12[(8 + wsc) * 64 + lane] = cg;
      }
    } else {                                       // iter 0 / drift: exact split scan
      int c0 = 0, c1 = 0, c2 = 0, c3 = 0;
      const ulonglong2* p = (const ulonglong2*)&rrk[half * 128];
      #pragma unroll 8
      for (int j = 0; j < 64; ++j) {
        const ulonglong2 kk = p[j];
        c0 += (kk.x < key) ? 1 : 0;
        c1 += (kk.y < key) ? 1 : 0;
      }
      cex[tid] = (c0 + c2) + (c1 + c3);
      if (half == 0) red12[(8 + wsc) * 64 + lane] = 0.0f;
    }
    __syncthreads();                               // B3: tcnt4, th_key, red12[8..11], cex

    // ---- P3: coef; backward from epb + own-wave cvec broadcast; base slots ----
    const int cm = tcnt4[0] + tcnt4[1] + tcnt4[2] + tcnt4[3];
    const float maxterm = ismax ? ((a / (float)cm) * 2.0f * u) : 0.0f;
    float coefv;
    if (__builtin_expect(valid, 1)) {
      coefv = 2.0f * u * (1.0f / 256.0f) + maxterm;     // rank-free!
    } else {
      const int cnt = cex[oid] + cex[256 + oid];
      if (half == 0 && cnt == THRANK) th_key = key;     // unique writer
      const float gfac = fminf(fmaxf((float)cnt + 1.0f - a256, 0.0f), 1.0f) * (1.0f / 256.0f);
      coefv = 2.0f * u * gfac + maxterm;
    }
    cvec8[w8 * 64 + lane] = coefv;                 // same-wave row: no barrier needed
    {
      const int lbase = half * 32;
      const float* cp = &cvec8[w8 * 64 + lbase];
      float q0 = 0.f, q1 = 0.f, q2 = 0.f, q3 = 0.f;
      #pragma unroll
      for (int q = 0; q < 8; ++q) {                // broadcast b128 reads of own row
        const float4 c4 = *(const float4*)&cp[4 * q];
        q0 = fmaf(c4.x, epb[4 * q + 0], q0);
        q1 = fmaf(c4.y, epb[4 * q + 1], q1);
        q2 = fmaf(c4.z, epb[4 * q + 2], q2);
        q3 = fmaf(c4.w, epb[4 * q + 3], q3);
      }
      red12[w8 * 64 + lane] = (q0 + q2) + (q1 + q3);
    }
    if (tid < 64) ckey[tid] = ~0ull;               // refill (read was P2; B3 separates)
    __syncthreads();                               // B4: red12[0..7]

    // ---- P4: 12-slot sum; step; projection from own-wave v row (broadcast b128) ----
    float s4 = 0.0f;
    #pragma unroll
    for (int k = 0; k < 12; ++k) s4 += red12[k * 64 + lane];
    cc = cc + LRATE * rl_f(s4, NY);                // gc = -sum(coef); col 50 = ones
    const float gz = s4 - gamma * yhl;
    const float v  = zv - LRATE * gz;
    if (lane < NY) vvec8[w8 * 52 + lane] = v;      // same-wave row

    float vq[52];
    {
      const float* vp = &vvec8[w8 * 52];
      #pragma unroll
      for (int i = 0; i < 13; ++i) {
        const float4 v4 = *(const float4*)&vp[4 * i];
        vq[4*i+0] = v4.x; vq[4*i+1] = v4.y; vq[4*i+2] = v4.z; vq[4*i+3] = v4.w;
      }
    }
    int ah0 = 0, ah1 = 0; float cs0 = 0.f, cs1 = 0.f;
    #pragma unroll
    for (int k = 0; k < NY; k += 2) {
      const bool b0 = (vq[k] > v)     || (vq[k] == v     && (k    ) > lane);
      const bool b1 = (vq[k + 1] > v) || (vq[k + 1] == v && (k + 1) > lane);
      ah0 += b0 ? 1 : 0;
      ah1 += b1 ? 1 : 0;
      cs0 += b0 ? vq[k] : 0.0f;
      cs1 += b1 ? vq[k + 1] : 0.0f;
    }
    const int   ahead = ah0 + ah1;
    const float css   = (cs0 + cs1) + v - 1.0f;
    const bool pc = (lane < NY) && (v - css / (float)(ahead + 1) > 0.0f);
    const int rho = __popcll(__ballot(pc));        // >= 1 always
    const unsigned long long bsel = __ballot((lane < NY) && (ahead == rho - 1));
    const int srcl = __ffsll(bsel) - 1;
    const float tau =
        __int_as_float(__builtin_amdgcn_readlane(__float_as_int(css), srcl)) / (float)rho;
    zv = (lane < NY) ? fmaxf(v - tau, 0.0f) : 0.0f;
    if (lane < NY) zvec8[w8 * 52 + lane] = zv;     // same-wave row for next P0
  }

  if (tid < 64 && lane < NY) out[t * NY + lane] = zv;   // wave 0

}

extern "C" void kernel_launch(void* const* d_in, const int* in_sizes, int n_in,
                              void* d_out, int out_size, void* d_ws, size_t ws_size,
                              hipStream_t stream) {
  (void)in_sizes; (void)n_in; (void)d_ws; (void)ws_size; (void)out_size;
  const float* X   = (const float*)d_in[0];
  const float* Y   = (const float*)d_in[1];
  const float* W   = (const float*)d_in[2];
  const float* B   = (const float*)d_in[3];
  const float* DLT = (const float*)d_in[4];
  const float* GMM = (const float*)d_in[5];
  float* out = (float*)d_out;
  hipLaunchKernelGGL(dro_kernel, dim3(NOBS), dim3(512), 0, stream,
                     X, Y, W, B, DLT, GMM, out);
}